// Round 3
// baseline (455.840 us; speedup 1.0000x reference)
//
#include <hip/hip_runtime.h>

#define BATCH 2048
#define TLEN  512
#define HID   64   // hidden size

typedef _Float16 f16x2 __attribute__((ext_vector_type(2)));

// Hard-coded v_dot2_f32_f16: d = a.lo*b.lo + a.hi*b.hi + c (fp32 accumulate).
// Inline asm with "v" constraints so (1) no cvt+fma fallback expansion and
// (2) operands must be arch VGPRs at use — makes AGPR-parking the weight
// array cost a v_accvgpr_read per use, pushing the RA to keep them in VGPRs.
__device__ __forceinline__ float fdot2_asm(unsigned int a, unsigned int b, float c) {
    float d;
    asm("v_dot2_f32_f16 %0, %1, %2, %3" : "=v"(d) : "v"(a), "v"(b), "v"(c));
    return d;
}

__device__ __forceinline__ unsigned int pk2(float a, float b) {
    f16x2 r; r[0] = (_Float16)a; r[1] = (_Float16)b;
    return __builtin_bit_cast(unsigned int, r);
}

__device__ __forceinline__ float rcp_fast(float x) {
    return __builtin_amdgcn_rcpf(x);
}

__device__ __forceinline__ float sigmoid_fast(float x) {
    // 1/(1+e^-x); e^-x -> inf for very negative x gives rcp(inf)=0: correct limit
    return rcp_fast(1.0f + __expf(-x));
}

__device__ __forceinline__ float tanh_fast(float x) {
    // tanh = 1 - 2/(e^{2x}+1); e^{2x} -> inf gives 1, -> 0 gives -1: correct limits
    return 1.0f - 2.0f * rcp_fast(__expf(2.0f * x) + 1.0f);
}

// One wave (64 lanes) per batch element. Lane j owns hidden unit j and gate
// rows {j, 64+j, 128+j, 192+j} of W_hh (PyTorch gate order i,f,g,o), kept in
// registers as 128 packed-f16 uints. h is broadcast through wave-private LDS.
__global__ __launch_bounds__(256) __attribute__((amdgpu_waves_per_eu(2, 2)))
void lstm_kernel(const float* __restrict__ x,
                 const float* __restrict__ W_ih,
                 const float* __restrict__ W_hh,
                 const float* __restrict__ b_ih,
                 const float* __restrict__ b_hh,
                 const float* __restrict__ W_d,
                 const float* __restrict__ b_d,
                 float* __restrict__ out) {
    __shared__ __align__(16) float    xs[4][TLEN];  // per-wave x row (8 KB)
    __shared__ __align__(16) _Float16 hs[4][HID];   // per-wave h broadcast (512 B)

    const int lane = threadIdx.x & 63;
    const int wave = threadIdx.x >> 6;
    const int b    = blockIdx.x * 4 + wave;

    float* xsw = xs[wave];
    _Float16* hsw = hs[wave];

    // ---- load this wave's x row into LDS (coalesced float4) ----
    {
        const float4* xr = reinterpret_cast<const float4*>(x + (size_t)b * TLEN);
        float4* xw = reinterpret_cast<float4*>(xsw);
        xw[lane]      = xr[lane];
        xw[lane + 64] = xr[lane + 64];
    }

    // ---- per-lane gate parameters (fp32) ----
    float wih[4], bias[4];
#pragma unroll
    for (int g = 0; g < 4; ++g) {
        const int r = g * HID + lane;
        wih[g]  = W_ih[r];               // input_size == 1
        bias[g] = b_ih[r] + b_hh[r];
    }

    // ---- W_hh rows -> registers as packed f16 pairs: w[g][p] = (W[r,2p],W[r,2p+1]) ----
    unsigned int w[4][32];
#pragma unroll
    for (int g = 0; g < 4; ++g) {
        const float4* wr = reinterpret_cast<const float4*>(W_hh + (size_t)(g * HID + lane) * HID);
#pragma unroll
        for (int q = 0; q < 16; ++q) {
            float4 v = wr[q];
            w[g][2 * q]     = pk2(v.x, v.y);
            w[g][2 * q + 1] = pk2(v.z, v.w);
        }
    }

    __threadfence_block();  // order x LDS writes before loop reads (wave-internal)

    // ---- recurrence ----
    float hval = 0.0f, cval = 0.0f;
    for (int t = 0; t < TLEN; ++t) {
        // broadcast h through LDS as f16 (wave-private buffer; in-order DS + fence)
        hsw[lane] = (_Float16)hval;
        __threadfence_block();

        const float xt = xsw[t];
        float a0 = fmaf(xt, wih[0], bias[0]);
        float a1 = fmaf(xt, wih[1], bias[1]);
        float a2 = fmaf(xt, wih[2], bias[2]);
        float a3 = fmaf(xt, wih[3], bias[3]);

        const uint4* hp = reinterpret_cast<const uint4*>(hsw);
#pragma unroll
        for (int ck = 0; ck < 8; ++ck) {
            const uint4 hv = hp[ck];  // 8 h values, broadcast read (conflict-free)
            const int p = 4 * ck;
            a0 = fdot2_asm(hv.x, w[0][p + 0], a0);
            a0 = fdot2_asm(hv.y, w[0][p + 1], a0);
            a0 = fdot2_asm(hv.z, w[0][p + 2], a0);
            a0 = fdot2_asm(hv.w, w[0][p + 3], a0);
            a1 = fdot2_asm(hv.x, w[1][p + 0], a1);
            a1 = fdot2_asm(hv.y, w[1][p + 1], a1);
            a1 = fdot2_asm(hv.z, w[1][p + 2], a1);
            a1 = fdot2_asm(hv.w, w[1][p + 3], a1);
            a2 = fdot2_asm(hv.x, w[2][p + 0], a2);
            a2 = fdot2_asm(hv.y, w[2][p + 1], a2);
            a2 = fdot2_asm(hv.z, w[2][p + 2], a2);
            a2 = fdot2_asm(hv.w, w[2][p + 3], a2);
            a3 = fdot2_asm(hv.x, w[3][p + 0], a3);
            a3 = fdot2_asm(hv.y, w[3][p + 1], a3);
            a3 = fdot2_asm(hv.z, w[3][p + 2], a3);
            a3 = fdot2_asm(hv.w, w[3][p + 3], a3);
        }

        const float gi = sigmoid_fast(a0);
        const float gf = sigmoid_fast(a1);
        const float gg = tanh_fast(a2);
        const float go = sigmoid_fast(a3);
        cval = fmaf(gf, cval, gi * gg);
        hval = go * tanh_fast(cval);
    }

    // ---- out[b] = sum_j h_j * W_d[j] + b_d ----
    float p = hval * W_d[lane];
#pragma unroll
    for (int off = 32; off > 0; off >>= 1)
        p += __shfl_xor(p, off, 64);
    if (lane == 0)
        out[b] = p + b_d[0];
}

extern "C" void kernel_launch(void* const* d_in, const int* in_sizes, int n_in,
                              void* d_out, int out_size, void* d_ws, size_t ws_size,
                              hipStream_t stream) {
    const float* x    = (const float*)d_in[0];
    const float* W_ih = (const float*)d_in[1];
    const float* W_hh = (const float*)d_in[2];
    const float* b_ih = (const float*)d_in[3];
    const float* b_hh = (const float*)d_in[4];
    const float* W_d  = (const float*)d_in[5];
    const float* b_d  = (const float*)d_in[6];
    float* out = (float*)d_out;

    dim3 grid(BATCH / 4);   // 512 blocks x 4 waves = 2048 waves (one per batch row)
    dim3 block(256);
    lstm_kernel<<<grid, block, 0, stream>>>(x, W_ih, W_hh, b_ih, b_hh, W_d, b_d, out);
}

// Round 4
// 285.886 us; speedup vs baseline: 1.5945x; 1.5945x over previous
//
#include <hip/hip_runtime.h>

#define TLEN 512
#define HID  64

typedef _Float16 half8 __attribute__((ext_vector_type(8)));
typedef float    f32x4 __attribute__((ext_vector_type(4)));

__device__ __forceinline__ float rcp_fast(float x) { return __builtin_amdgcn_rcpf(x); }
__device__ __forceinline__ float sigmoid_fast(float x) { return rcp_fast(1.0f + __expf(-x)); }
__device__ __forceinline__ float tanh_fast(float x) { return 1.0f - 2.0f * rcp_fast(__expf(2.0f * x) + 1.0f); }

// 256 blocks x 8 waves. Block owns 8 batch rows (M=8 of the 16x16x32 MFMA's M;
// rows 8-15 are harmless duplicates). Wave w owns gate cols [32w,32w+32) as
// N-tiles {2w,2w+1}; K=64 as two k-chunks -> 4 MFMA/wave/step. W_hh B-frags
// are 16 VGPRs/lane, resident in the unified VGPR/AGPR file (MFMA can read
// AGPRs directly -- the R1-R3 dot2 design died on exactly this: VALU can't).
// Per-step: MFMA -> gates to LDS -> barrier -> per-lane (row,unit) activation
// in fp32 -> h (f16) to LDS -> barrier -> next A-frags via ds_read_b128.
__global__ __launch_bounds__(512)
void lstm_mfma(const float* __restrict__ x,
               const float* __restrict__ W_ih,
               const float* __restrict__ W_hh,
               const float* __restrict__ b_ih,
               const float* __restrict__ b_hh,
               const float* __restrict__ W_d,
               const float* __restrict__ b_d,
               float* __restrict__ out) {
    __shared__ __align__(16) float    xs[8][516];    // x rows, stride 516 breaks bank aliasing
    __shared__ __align__(16) float    gates[8][260]; // [row][gate], stride 260: conflict-free writes
    __shared__ __align__(16) _Float16 hbuf[8][72];   // [row][k] f16, stride 72 (144B, 16B-aligned)

    const int tid = threadIdx.x;
    const int L   = tid & 63;
    const int w   = tid >> 6;          // wave 0..7
    const int r0  = blockIdx.x * 8;    // first batch row of this block

    // ---- stage x rows into LDS; zero hbuf (h0 = 0) ----
    for (int i = tid; i < 8 * TLEN; i += 512) {
        int r = i >> 9, t = i & 511;
        xs[r][t] = x[(size_t)(r0 + r) * TLEN + t];
    }
    {
        _Float16* hz = &hbuf[0][0];
        for (int i = tid; i < 8 * 72; i += 512) hz[i] = (_Float16)0.0f;
    }

    // ---- per-lane activation position: row m, hidden unit j ----
    const int m = L & 7;
    const int j = 8 * w + (L >> 3);

    float wih[4], bias[4];
#pragma unroll
    for (int g = 0; g < 4; ++g) {
        const int row = g * HID + j;   // PyTorch gate order i,f,g,o
        wih[g]  = W_ih[row];           // input_size == 1
        bias[g] = b_ih[row] + b_hh[row];
    }

    // ---- B-frags: B[k][n] with n = L&15, k = 32q + (L>>4)*8 + jj ----
    // B[k][n] = W_hh[16T + n][k]  (gates = h @ W_hh^T)
    half8 bf[2][2];
#pragma unroll
    for (int tt = 0; tt < 2; ++tt) {
        const int wr = 16 * (2 * w + tt) + (L & 15);
#pragma unroll
        for (int q = 0; q < 2; ++q) {
            const float* p = &W_hh[(size_t)wr * HID + 32 * q + (L >> 4) * 8];
            float4 v0 = *(const float4*)p;
            float4 v1 = *(const float4*)(p + 4);
            half8 hf;
            hf[0] = (_Float16)v0.x; hf[1] = (_Float16)v0.y;
            hf[2] = (_Float16)v0.z; hf[3] = (_Float16)v0.w;
            hf[4] = (_Float16)v1.x; hf[5] = (_Float16)v1.y;
            hf[6] = (_Float16)v1.z; hf[7] = (_Float16)v1.w;
            bf[tt][q] = hf;
        }
    }

    // ---- loop-invariant LDS addresses ----
    // A-frag: A[mm][k], mm = L&15 -> read h row (mm&7) (rows 8-15 duplicate rows 0-7)
    const _Float16* aptr0 = &hbuf[L & 7][(L >> 4) * 8];        // k-chunk q=0
    const _Float16* aptr1 = aptr0 + 32;                        // k-chunk q=1
    // C/D: col = L&15, row = (L>>4)*4 + reg; lanes 0..31 hold real rows 0..7
    const int wrow = ((L >> 4) & 1) * 4;
    float* gw0 = &gates[wrow][16 * (2 * w)     + (L & 15)];    // + reg*260
    float* gw1 = &gates[wrow][16 * (2 * w + 1) + (L & 15)];
    const float* grd = &gates[m][j];

    const f32x4 zero = {0.0f, 0.0f, 0.0f, 0.0f};
    float cst = 0.0f;

    __syncthreads();

    for (int t = 0; t < TLEN; ++t) {
        // gates[16 x 32-chunk of N] = h @ W_hh^T  (fp32 accumulate)
        half8 a0 = *(const half8*)aptr0;
        half8 a1 = *(const half8*)aptr1;
        f32x4 d0 = __builtin_amdgcn_mfma_f32_16x16x32_f16(a0, bf[0][0], zero, 0, 0, 0);
        d0       = __builtin_amdgcn_mfma_f32_16x16x32_f16(a1, bf[0][1], d0,   0, 0, 0);
        f32x4 d1 = __builtin_amdgcn_mfma_f32_16x16x32_f16(a0, bf[1][0], zero, 0, 0, 0);
        d1       = __builtin_amdgcn_mfma_f32_16x16x32_f16(a1, bf[1][1], d1,   0, 0, 0);

        if (L < 32) {
#pragma unroll
            for (int r = 0; r < 4; ++r) {
                gw0[r * 260] = d0[r];
                gw1[r * 260] = d1[r];
            }
        }
        __syncthreads();

        // per-lane position (m, j): fold xproj + bias, activate, update c,h
        const float xt = xs[m][t];
        const float ai = grd[0]   + fmaf(xt, wih[0], bias[0]);
        const float af = grd[64]  + fmaf(xt, wih[1], bias[1]);
        const float ag = grd[128] + fmaf(xt, wih[2], bias[2]);
        const float ao = grd[192] + fmaf(xt, wih[3], bias[3]);
        const float gi = sigmoid_fast(ai);
        const float gf = sigmoid_fast(af);
        const float gg = tanh_fast(ag);
        const float go = sigmoid_fast(ao);
        cst = fmaf(gf, cst, gi * gg);
        const float hv = go * tanh_fast(cst);
        hbuf[m][j] = (_Float16)hv;
        __syncthreads();
    }

    // ---- epilogue: wave w reduces row w:  out[r0+w] = h . W_d + b_d ----
    float pv = (float)hbuf[w][L] * W_d[L];
#pragma unroll
    for (int off = 32; off > 0; off >>= 1)
        pv += __shfl_xor(pv, off, 64);
    if (L == 0)
        out[r0 + w] = pv + b_d[0];
}

extern "C" void kernel_launch(void* const* d_in, const int* in_sizes, int n_in,
                              void* d_out, int out_size, void* d_ws, size_t ws_size,
                              hipStream_t stream) {
    const float* x    = (const float*)d_in[0];
    const float* W_ih = (const float*)d_in[1];
    const float* W_hh = (const float*)d_in[2];
    const float* b_ih = (const float*)d_in[3];
    const float* b_hh = (const float*)d_in[4];
    const float* W_d  = (const float*)d_in[5];
    const float* b_d  = (const float*)d_in[6];
    float* out = (float*)d_out;

    dim3 grid(256);    // 2048 rows / 8 rows per block
    dim3 block(512);   // 8 waves
    lstm_mfma<<<grid, block, 0, stream>>>(x, W_ih, W_hh, b_ih, b_hh, W_d, b_d, out);
}